// Round 5
// baseline (386.760 us; speedup 1.0000x reference)
//
#include <hip/hip_runtime.h>

// Fully-fused MLP, Round 8: weight stream AMORTIZED 4x.
//
// Round-7 analysis: streaming all 38 weight frags per 16-row tile moves
// 4.8 GB through the LDS pipe (38 KB x 4096 waves x 32 iters) -> LDS-BW
// floor ~70-105 us. Fix: each wave runs FOUR independent 16-row streams
// per iteration, so each 8-frag chunk is read once and feeds 32 MFMAs
// (weight LDS traffic /4 = 1.2 GB, ~20 TB/s at target pace).
//
// Kept from round 7: phi-telescope zero-shuffle datapath (acc -> next
// layer's B-frags in-register), frag-major weight store in LDS (lane i
// reads byte 16i, conflict-free), X/Y double-buffer with 6-stage parity:
//   stage:   L0(W0) Wh0  Wh1  Wh2  Wh3  Wo
//   compute:   X     Y    X    Y    X    Y
//   read:      Y     X    Y    X    Y    X[0..3](W0, next iter)
// Per stage: 8 ds_read_b128 hidden under 4 streams x (24 VALU + 8 MFMA).
//
// 8 independent chains/SIMD (2 waves x 4 streams); x loaded raw one full
// iteration ahead, converted per-stream at L0 so raw regs die as acc is
// born. Register image ~220-240 -> __launch_bounds__(256,2).

typedef __attribute__((ext_vector_type(8))) short short8;   // 8 x bf16 frag
typedef __attribute__((ext_vector_type(4))) float f32x4;    // MFMA acc

#define BATCH   2097152
#define NBLOCKS 1024
#define NWAVES  (NBLOCKS * 4)                 // 4096 waves
#define ROWS_PW 64                            // 4 streams x 16 rows / iter
#define ITERS   (BATCH / (NWAVES * ROWS_PW))  // 8
static_assert(BATCH == (size_t)NWAVES * ROWS_PW * ITERS, "");

// packed f32x2 -> bf16x2, RNE, single instruction (no builtin on gfx950)
__device__ __forceinline__ unsigned cvt_pk(float a, float b) {
    unsigned r;
    asm("v_cvt_pk_bf16_f32 %0, %1, %2" : "=v"(r) : "v"(a), "v"(b));
    return r;
}

__global__ __launch_bounds__(256, 2)
void mlp_fused(const float* __restrict__ x, const float* __restrict__ W0,
               const float* __restrict__ Wh, const float* __restrict__ Wo,
               float* __restrict__ out)
{
    // frag-major weight store: frag f, lane l at wlds[f][l] (16 B units)
    // f: W0 t -> t | Wh l,t,c -> 4 + 8l + 2t + c | Wo c -> 36 + c
    __shared__ short8 wlds[38][64];

    const int tid  = threadIdx.x;
    const int w    = tid >> 6;
    const int lane = tid & 63;
    const int n = lane & 15;         // A: m index / B: batch col / C: col
    const int q = lane >> 4;         // k-group (A,B) / row-group (C)

    const int gw = blockIdx.x * 4 + w;

    // issue batch-0 x loads before the weight preamble (overlap HBM latency)
    f32x4 raw[4][2];
    {
        const size_t r = (size_t)gw * ROWS_PW;
        #pragma unroll
        for (int st = 0; st < 4; ++st) {
            const f32x4* p = (const f32x4*)(x + (r + 16 * st + n) * 32) + 2 * q;
            raw[st][0] = p[0]; raw[st][1] = p[1];
        }
    }

    // phi_t(n): weight column for tile t held at A-frag m-index n
    int phi[4];
    #pragma unroll
    for (int t = 0; t < 4; ++t)
        phi[t] = 32 * (t >> 1) + 8 * (n >> 2) + 4 * (t & 1) + (n & 3);

    // ---- preamble: waves cooperatively build all frags into LDS ----------
    auto build = [&](const float* p) -> short8 {   // p = &W[k0][col], stride 64
        union { unsigned u[4]; short8 s; } f;
        #pragma unroll
        for (int i = 0; i < 4; ++i)
            f.u[i] = cvt_pk(p[(2 * i) * 64], p[(2 * i + 1) * 64]);
        return f.s;
    };
    if (w == 0) {
        #pragma unroll
        for (int t = 0; t < 4; ++t)                                  // W0 [32][64]
            wlds[t][lane] = build(W0 + (8 * q) * 64 + phi[t]);
        #pragma unroll
        for (int t = 0; t < 4; ++t)                                  // Wh layer 3
            #pragma unroll
            for (int c = 0; c < 2; ++c)
                wlds[28 + 2 * t + c][lane] =
                    build(Wh + 3 * 4096 + (32 * c + 8 * q) * 64 + phi[t]);
        #pragma unroll
        for (int c = 0; c < 2; ++c) {                                // Wo [64][3]
            union { unsigned u[4]; short8 s; } f;
            #pragma unroll
            for (int i = 0; i < 4; ++i) {
                float a = (n < 3) ? Wo[(32 * c + 8 * q + 2 * i)     * 3 + n] : 0.f;
                float b = (n < 3) ? Wo[(32 * c + 8 * q + 2 * i + 1) * 3 + n] : 0.f;
                f.u[i] = cvt_pk(a, b);
            }
            wlds[36 + c][lane] = f.s;
        }
    } else {
        const int l = w - 1;                                         // Wh 0..2
        #pragma unroll
        for (int t = 0; t < 4; ++t)
            #pragma unroll
            for (int c = 0; c < 2; ++c)
                wlds[4 + 8 * l + 2 * t + c][lane] =
                    build(Wh + l * 4096 + (32 * c + 8 * q) * 64 + phi[t]);
    }
    __syncthreads();

    const f32x4 z = {0.f, 0.f, 0.f, 0.f};
    short8 X[8], Y[8];

    // prime: X[0..3] = W0 frags
    #pragma unroll
    for (int j = 0; j < 4; ++j) X[j] = wlds[j][lane];

    // ReLU + pack acc -> next layer's B-frags, pure in-register
    auto packact = [&](const f32x4 (&acc)[4], short8& b0, short8& b1) {
        union { unsigned u[4]; short8 s; } A, B;
        A.u[0] = cvt_pk(fmaxf(acc[0][0], 0.f), fmaxf(acc[0][1], 0.f));
        A.u[1] = cvt_pk(fmaxf(acc[0][2], 0.f), fmaxf(acc[0][3], 0.f));
        A.u[2] = cvt_pk(fmaxf(acc[1][0], 0.f), fmaxf(acc[1][1], 0.f));
        A.u[3] = cvt_pk(fmaxf(acc[1][2], 0.f), fmaxf(acc[1][3], 0.f));
        B.u[0] = cvt_pk(fmaxf(acc[2][0], 0.f), fmaxf(acc[2][1], 0.f));
        B.u[1] = cvt_pk(fmaxf(acc[2][2], 0.f), fmaxf(acc[2][3], 0.f));
        B.u[2] = cvt_pk(fmaxf(acc[3][0], 0.f), fmaxf(acc[3][1], 0.f));
        B.u[3] = cvt_pk(fmaxf(acc[3][2], 0.f), fmaxf(acc[3][3], 0.f));
        b0 = A.s; b1 = B.s;
    };

    #pragma unroll 1
    for (int it = 0; it < ITERS; ++it) {
        const size_t row0 = ((size_t)it * NWAVES + gw) * ROWS_PW;
        f32x4 acc[4][4];

        // ---- S0: read Wh0 -> Y; per stream: convert x, 4 L0 MFMAs --------
        #pragma unroll
        for (int j = 0; j < 8; ++j) Y[j] = wlds[4 + j][lane];
        #pragma unroll
        for (int st = 0; st < 4; ++st) {
            union { unsigned u[4]; short8 s; } f;
            f.u[0] = cvt_pk(raw[st][0][0], raw[st][0][1]);
            f.u[1] = cvt_pk(raw[st][0][2], raw[st][0][3]);
            f.u[2] = cvt_pk(raw[st][1][0], raw[st][1][1]);
            f.u[3] = cvt_pk(raw[st][1][2], raw[st][1][3]);
            #pragma unroll
            for (int t = 0; t < 4; ++t)
                acc[st][t] = __builtin_amdgcn_mfma_f32_16x16x32_bf16(
                                 X[t], f.s, z, 0, 0, 0);
        }
        // raw regs all dead -> issue next iteration's x loads now
        if (it + 1 < ITERS) {
            const size_t r = ((size_t)(it + 1) * NWAVES + gw) * ROWS_PW;
            #pragma unroll
            for (int st = 0; st < 4; ++st) {
                const f32x4* p = (const f32x4*)(x + (r + 16 * st + n) * 32) + 2 * q;
                raw[st][0] = p[0]; raw[st][1] = p[1];
            }
        }

        // ---- S1: read Wh1 -> X; compute Wh0 from Y -----------------------
        #pragma unroll
        for (int j = 0; j < 8; ++j) X[j] = wlds[12 + j][lane];
        #pragma unroll
        for (int st = 0; st < 4; ++st) {
            short8 b0, b1;
            packact(acc[st], b0, b1);
            #pragma unroll
            for (int t = 0; t < 4; ++t)
                acc[st][t] = __builtin_amdgcn_mfma_f32_16x16x32_bf16(
                                 Y[2 * t], b0, z, 0, 0, 0);
            #pragma unroll
            for (int t = 0; t < 4; ++t)
                acc[st][t] = __builtin_amdgcn_mfma_f32_16x16x32_bf16(
                                 Y[2 * t + 1], b1, acc[st][t], 0, 0, 0);
        }

        // ---- S2: read Wh2 -> Y; compute Wh1 from X -----------------------
        #pragma unroll
        for (int j = 0; j < 8; ++j) Y[j] = wlds[20 + j][lane];
        #pragma unroll
        for (int st = 0; st < 4; ++st) {
            short8 b0, b1;
            packact(acc[st], b0, b1);
            #pragma unroll
            for (int t = 0; t < 4; ++t)
                acc[st][t] = __builtin_amdgcn_mfma_f32_16x16x32_bf16(
                                 X[2 * t], b0, z, 0, 0, 0);
            #pragma unroll
            for (int t = 0; t < 4; ++t)
                acc[st][t] = __builtin_amdgcn_mfma_f32_16x16x32_bf16(
                                 X[2 * t + 1], b1, acc[st][t], 0, 0, 0);
        }

        // ---- S3: read Wh3 -> X; compute Wh2 from Y -----------------------
        #pragma unroll
        for (int j = 0; j < 8; ++j) X[j] = wlds[28 + j][lane];
        #pragma unroll
        for (int st = 0; st < 4; ++st) {
            short8 b0, b1;
            packact(acc[st], b0, b1);
            #pragma unroll
            for (int t = 0; t < 4; ++t)
                acc[st][t] = __builtin_amdgcn_mfma_f32_16x16x32_bf16(
                                 Y[2 * t], b0, z, 0, 0, 0);
            #pragma unroll
            for (int t = 0; t < 4; ++t)
                acc[st][t] = __builtin_amdgcn_mfma_f32_16x16x32_bf16(
                                 Y[2 * t + 1], b1, acc[st][t], 0, 0, 0);
        }

        // ---- S4: read Wo -> Y[0..1]; compute Wh3 from X ------------------
        Y[0] = wlds[36][lane];
        Y[1] = wlds[37][lane];
        #pragma unroll
        for (int st = 0; st < 4; ++st) {
            short8 b0, b1;
            packact(acc[st], b0, b1);
            #pragma unroll
            for (int t = 0; t < 4; ++t)
                acc[st][t] = __builtin_amdgcn_mfma_f32_16x16x32_bf16(
                                 X[2 * t], b0, z, 0, 0, 0);
            #pragma unroll
            for (int t = 0; t < 4; ++t)
                acc[st][t] = __builtin_amdgcn_mfma_f32_16x16x32_bf16(
                                 X[2 * t + 1], b1, acc[st][t], 0, 0, 0);
        }

        // ---- S5: read W0 -> X[0..3] (next iter); output layer from Y -----
        #pragma unroll
        for (int j = 0; j < 4; ++j) X[j] = wlds[j][lane];
        #pragma unroll
        for (int st = 0; st < 4; ++st) {
            short8 b0, b1;
            packact(acc[st], b0, b1);
            f32x4 o = __builtin_amdgcn_mfma_f32_16x16x32_bf16(Y[0], b0, z, 0, 0, 0);
            o = __builtin_amdgcn_mfma_f32_16x16x32_bf16(Y[1], b1, o, 0, 0, 0);
            if (lane < 16) {
                float* po = out + (row0 + 16 * st + lane) * 3;
                po[0] = o[0]; po[1] = o[1]; po[2] = o[2];
            }
        }
    }
}

extern "C" void kernel_launch(void* const* d_in, const int* in_sizes, int n_in,
                              void* d_out, int out_size, void* d_ws, size_t ws_size,
                              hipStream_t stream) {
    (void)in_sizes; (void)n_in; (void)d_ws; (void)ws_size; (void)out_size;
    const float* x  = (const float*)d_in[0];
    const float* W0 = (const float*)d_in[1];
    const float* Wh = (const float*)d_in[2];
    const float* Wo = (const float*)d_in[3];
    float* out = (float*)d_out;
    mlp_fused<<<NBLOCKS, 256, 0, stream>>>(x, W0, Wh, Wo, out);
}